// Round 7
// baseline (149.085 us; speedup 1.0000x reference)
//
#include <hip/hip_runtime.h>
#include <math.h>
#include <string.h>

#define N 12288
#define QP 7168           // padded compact count = 56*128
#define BT 1024           // build-kernel threads per block
#define BB 12             // build-kernel blocks (N / BT)
#define G2 224            // nnloss blocks
#define QG 32             // queries per nnloss block (224*32 = 7168)
#define NST 8             // candidate stripes per block (half-wave each)
#define SL 896            // stripe length = QP / NST

typedef unsigned long long ull;

struct CMat { float c[6][6]; };

// ---------------------------------------------------------------------------
// Kernel 1: order-preserving compaction (round-3 version, unchanged math).
// Block b owns [b*1024,(b+1)*1024); global write base computed redundantly
// (recount sdf of blocks [0,b): block-uniform, L2-broadcast). Ordering key
// (block, wave, lane) == ascending original index. Block 11 stores M and
// sentinel-pads pts[M..QP). Zeroes the finalize ticket (dispatch boundary
// guarantees visibility to kernel 2). No best[] array needed anymore.
// ---------------------------------------------------------------------------
__global__ __launch_bounds__(1024) void build_kernel(
    const float* __restrict__ new_xyz,
    const float* __restrict__ gt_sdf,
    float4* __restrict__ pts,
    int* __restrict__ cj,
    int* __restrict__ Mout,
    unsigned int* __restrict__ ticket)
{
    const int tid = threadIdx.x;
    const int b = blockIdx.x;        // 0..11
    const int lane = tid & 63;
    const int wave = tid >> 6;       // 0..15

    // global prefix: #inside in [0, b*1024), redundant per block
    int cpre = 0;
    #pragma unroll
    for (int r = 0; r < BB - 1; ++r) {
        const float sv = (r < b) ? gt_sdf[r * BT + tid] : 1.0f;
        cpre += (sv < 1e-8f) ? 1 : 0;
    }
    #pragma unroll
    for (int off = 32; off > 0; off >>= 1)
        cpre += __shfl_down(cpre, off, 64);      // lane0: wave partial

    // own range: flags + wave ballot rank
    const int idx = b * BT + tid;
    const float px = new_xyz[3 * idx + 0];
    const float py = new_xyz[3 * idx + 1];
    const float pz = new_xyz[3 * idx + 2];
    const bool ins = gt_sdf[idx] < 1e-8f;
    const ull m = __ballot(ins);
    const int rank = __popcll(m & ((1ull << lane) - 1ull));

    __shared__ int wpre[16];
    __shared__ int wcnt[16];
    __shared__ int woff[16];
    __shared__ int tot_s;
    if (lane == 0) { wpre[wave] = cpre; wcnt[wave] = __popcll(m); }
    __syncthreads();
    if (tid == 0) {
        int cb = 0;
        for (int w = 0; w < 16; ++w) cb += wpre[w];
        int run = cb;
        for (int w = 0; w < 16; ++w) { woff[w] = run; run += wcnt[w]; }
        tot_s = run;
    }
    __syncthreads();

    const int slot = woff[wave] + rank;
    if (ins && slot < QP) {
        pts[slot] = make_float4(-2.0f * px, -2.0f * py, -2.0f * pz,
                                px * px + py * py + pz * pz);
        cj[slot] = idx;
    }

    if (b == 0 && tid == 0) *ticket = 0u;

    if (b == BB - 1) {
        const int M = tot_s;
        if (tid == 0) *Mout = M;
        for (int s = M + tid; s < QP; s += BT)
            pts[s] = make_float4(0.0f, 0.0f, 0.0f, 3e30f);
    }
}

// ---------------------------------------------------------------------------
// Kernel 2: fused NN + loss, NO cross-block NN combine. Block g owns queries
// [g*32, g*32+32). Thread (qi=tid&31, st=tid>>5): query g*32+qi vs candidate
// stripe [st*896, st*896+896) capped at M (sentinels beyond M never win; the
// candidate set = all k<M minus self == previous rounds' effective set).
// Same fma chain (z,y,x), strict < ascending k => leftmost min per stripe;
// LDS u64 combine over stripes in one block (packed monotone-key<<32 | idx,
// min == global leftmost min == previous atomicMin/56-split winner exactly).
// All 64 lanes of each half-wave... (32 lanes) read the same pts[k] ->
// hardware broadcast; pts is 112KB, L1/L2 resident.
// Loss: lanes 0..31 of wave 0 run the identical strain quadratic form; the
// 64-lane shuffle tree (lanes 32..63 contribute 0) gives partial_sum[g];
// last-ticket block (of 224) sums partials in a fixed deterministic order.
// NOTE: q^2 values are bit-identical to prior rounds; only the double-sum
// ORDER changes (224 groups vs 28x4) -> output equal or within 1 ulp.
// ---------------------------------------------------------------------------
template<bool CAREFUL>
__device__ __forceinline__ void stripe_scan(
    const float4* __restrict__ pts, int kb, int lim, int ci,
    float wx, float wy, float wz, float* bd, int* bk)
{
    #pragma unroll 8
    for (int k = 0; k < lim; ++k) {
        const float4 b = pts[kb + k];
        float t = fmaf(wz, b.z, b.w);
        t = fmaf(wy, b.y, t);
        t = fmaf(wx, b.x, t);
        bool ok = t < *bd;
        if (CAREFUL) ok = ok && (kb + k != ci);
        if (ok) { *bd = t; *bk = k; }
    }
}

__global__ __launch_bounds__(256, 4) void nnloss_kernel(
    const float* __restrict__ new_xyz,
    const float* __restrict__ xyz,
    const float4* __restrict__ pts,
    const int* __restrict__ cj,
    const int* __restrict__ Mptr,
    double* __restrict__ partial_sum,
    unsigned int* __restrict__ partial_cnt,
    unsigned int* __restrict__ ticket,
    float* __restrict__ out,
    CMat C)
{
    const int tid = threadIdx.x;
    const int g = blockIdx.x;        // 0..223
    const int lane = tid & 63;
    const int qi = tid & 31;
    const int st = tid >> 5;         // 0..7
    const int qbase = g * QG;
    const int M = *Mptr;
    const bool active = (qbase < M);

    __shared__ ull sb[NST][QG];      // per-stripe packed winners (2 KB)
    __shared__ bool sdone;

    // ========================= NN phase ====================================
    if (active) {
        const int ci = qbase + qi;
        const float4 q = pts[ci];
        const float wx = -0.5f * q.x;          // recover raw coords (exact)
        const float wy = -0.5f * q.y;
        const float wz = -0.5f * q.z;

        float bd = 3.0e38f;
        int bk = 0;
        const int kb = st * SL;
        int lim = M - kb;
        lim = (lim > SL) ? SL : lim;           // may be <= 0 (all-sentinel)

        // the block's 32 queries lie entirely within one stripe (896 = 28*32)
        if (st == qbase / SL)
            stripe_scan<true>(pts, kb, lim, ci, wx, wy, wz, &bd, &bk);
        else
            stripe_scan<false>(pts, kb, lim, ci, wx, wy, wz, &bd, &bk);

        unsigned u = __float_as_uint(bd);
        u = ((int)u < 0) ? ~u : (u | 0x80000000u);
        sb[st][qi] = ((ull)u << 32) | (ull)(unsigned)(kb + bk);
    }
    __syncthreads();

    // ========================= loss phase (wave 0) =========================
    double red = 0.0;
    unsigned cnt = 0;
    if (tid < 64) {
        double q2 = 0.0;
        bool valid = false;
        if (active && lane < 32) {
            const int ci = qbase + lane;
            ull best = sb[0][lane];
            #pragma unroll
            for (int s2 = 1; s2 < NST; ++s2) {
                const ull p = sb[s2][lane];
                best = (p < best) ? p : best;
            }

            const bool real = (ci < M);
            const unsigned u = (unsigned)(best >> 32);
            const unsigned bits = (u & 0x80000000u) ? (u ^ 0x80000000u) : ~u;
            const float key = __uint_as_float(bits);   // min (sqj - 2*dot)
            const int cc = real ? (int)(unsigned)(best & 0xffffffffu) : 0;

            const int i  = real ? cj[ci] : 0;
            const int nn = cj[cc];

            const float wix = new_xyz[3 * i + 0];
            const float wiy = new_xyz[3 * i + 1];
            const float wiz = new_xyz[3 * i + 2];
            const float sqi = wix * wix + wiy * wiy + wiz * wiz;

            const float d2 = sqi + key;
            const float nnd = sqrtf(fmaxf(d2, 0.0f));
            valid = real && (nnd > 1e-8f);

            float qv = 0.0f;
            if (valid) {
                const float xix = xyz[3 * i + 0], xiy = xyz[3 * i + 1], xiz = xyz[3 * i + 2];
                const float wnx = new_xyz[3 * nn + 0], wny = new_xyz[3 * nn + 1], wnz = new_xyz[3 * nn + 2];
                const float xnx = xyz[3 * nn + 0],     xny = xyz[3 * nn + 1],     xnz = xyz[3 * nn + 2];

                const float du = (wnx - xnx) - (wix - xix);
                const float dv = (wny - xny) - (wiy - xiy);
                const float dw = (wnz - xnz) - (wiz - xiz);
                const float dx = wnx - wix + 1e-8f;
                const float dy = wny - wiy + 1e-8f;
                const float dz = wnz - wiz + 1e-8f;

                float et[6];
                et[0] = du / dx;
                et[1] = dv / dy;
                et[2] = dw / dz;
                et[3] = (du / dy + dv / dx) * 0.5f;
                et[4] = (du / dz + dw / dx) * 0.5f;
                et[5] = (dw / dy + dv / dz) * 0.5f;

                #pragma unroll
                for (int a = 0; a < 6; ++a) {
                    float s2 = 0.0f;
                    #pragma unroll
                    for (int b2 = 0; b2 < 6; ++b2) s2 += C.c[a][b2] * et[b2];
                    qv += et[a] * s2;
                }
            }
            q2 = (double)qv * (double)qv;
        }

        #pragma unroll
        for (int off = 32; off > 0; off >>= 1)
            q2 += __shfl_down(q2, off, 64);
        red = q2;                               // lane0 holds wave sum
        cnt = (unsigned)__popcll(__ballot(valid));
    }

    if (tid == 0) {
        partial_sum[g] = red;
        partial_cnt[g] = cnt;
        __threadfence();                        // release partials
        const unsigned t = atomicAdd(ticket, 1u);
        sdone = (t == G2 - 1);                  // last block finalizes
    }
    __syncthreads();

    // ========================= finalize (last block) =======================
    if (sdone && tid < 64) {
        __threadfence();                        // acquire side
        double s = 0.0, c = 0.0;
        #pragma unroll
        for (int j = 0; j < 4; ++j) {
            const int idx = tid * 4 + j;        // fixed deterministic order
            if (idx < G2) {
                s += partial_sum[idx];
                c += (double)partial_cnt[idx];
            }
        }
        #pragma unroll
        for (int off = 32; off > 0; off >>= 1) {
            s += __shfl_down(s, off, 64);
            c += __shfl_down(c, off, 64);
        }
        if (tid == 0) out[0] = (float)(sqrt(s) / c);
    }
}

// ---------------- Host: build C = inv(Ci) -----------------------------------
static void build_cmat(CMat* M)
{
    const double VP = 0.4, EP = 0.21;
    double A[6][12];
    memset(A, 0, sizeof(A));
    double Ci[6][6];
    memset(Ci, 0, sizeof(Ci));
    Ci[0][0] = 1.0 / EP; Ci[0][1] = -VP / EP; Ci[0][2] = -VP / EP;
    Ci[1][0] = -VP / EP; Ci[1][1] = 1.0 / EP; Ci[1][2] = -VP / EP;
    Ci[2][0] = -VP;      Ci[2][1] = -VP;      Ci[2][2] = 1.0 / EP;
    Ci[3][3] = 2.0 * (1.0 + VP) / EP;
    Ci[4][4] = Ci[3][3];
    Ci[5][5] = Ci[3][3];

    for (int i = 0; i < 6; ++i) {
        for (int j = 0; j < 6; ++j) A[i][j] = Ci[i][j];
        A[i][6 + i] = 1.0;
    }
    for (int col = 0; col < 6; ++col) {
        int piv = col;
        for (int r = col + 1; r < 6; ++r)
            if (fabs(A[r][col]) > fabs(A[piv][col])) piv = r;
        if (piv != col)
            for (int c = 0; c < 12; ++c) { double t = A[col][c]; A[col][c] = A[piv][c]; A[piv][c] = t; }
        const double d = A[col][col];
        for (int c = 0; c < 12; ++c) A[col][c] /= d;
        for (int r = 0; r < 6; ++r) {
            if (r == col) continue;
            const double f = A[r][col];
            if (f == 0.0) continue;
            for (int c = 0; c < 12; ++c) A[r][c] -= f * A[col][c];
        }
    }
    for (int i = 0; i < 6; ++i)
        for (int j = 0; j < 6; ++j)
            M->c[i][j] = (float)A[i][6 + j];
}

extern "C" void kernel_launch(void* const* d_in, const int* in_sizes, int n_in,
                              void* d_out, int out_size, void* d_ws, size_t ws_size,
                              hipStream_t stream)
{
    const float* new_xyz = (const float*)d_in[0];
    const float* xyz     = (const float*)d_in[1];
    const float* gt_sdf  = (const float*)d_in[2];
    float* out = (float*)d_out;

    // workspace layout (all consumed slots written before read):
    //   [0,      QP*16) : pts  float4 compacted inside points   (112 KB)
    //   [+,      QP*4)  : cj   original indices                 (28 KB)
    //   [+,      16)    : M    compact count
    //   then G2 doubles + G2 uints + 1 uint ticket
    char* p = (char*)d_ws;
    float4* pts = (float4*)p;                    p += (size_t)QP * 16;
    int* cj = (int*)p;                           p += (size_t)QP * 4;
    int* Mptr = (int*)p;                         p += 16;
    double* partial_sum = (double*)p;            p += G2 * sizeof(double);
    unsigned int* partial_cnt = (unsigned int*)p; p += G2 * sizeof(unsigned int);
    unsigned int* ticket = (unsigned int*)p;

    CMat C;
    build_cmat(&C);

    build_kernel<<<BB, BT, 0, stream>>>(new_xyz, gt_sdf, pts, cj, Mptr, ticket);
    nnloss_kernel<<<G2, 256, 0, stream>>>(new_xyz, xyz, pts, cj, Mptr,
                                          partial_sum, partial_cnt, ticket,
                                          out, C);
}

// Round 8
// 89.300 us; speedup vs baseline: 1.6695x; 1.6695x over previous
//
#include <hip/hip_runtime.h>
#include <math.h>
#include <string.h>

#define N 12288
#define QP 7168           // padded compact count = 56*128
#define TILE 128          // candidates per split (LDS tile)
#define NSPLIT 56         // QP / TILE
#define ACCS 2            // queries per thread
#define QBLK 512          // queries per block
#define NQB 14            // QP / QBLK
#define BT 1024           // build-kernel threads per block
#define BB 12             // build-kernel blocks (N / BT)
#define NPART (QP / 256)  // 28 loss partials

typedef unsigned long long ull;

struct CMat { float c[6][6]; };

// ---------------------------------------------------------------------------
// Kernel 1: order-preserving compaction (round-3 version, unchanged math).
// Block b owns [b*1024,(b+1)*1024); global write base computed redundantly
// (recount sdf of blocks [0,b): block-uniform, L2-broadcast). Ordering key
// (block, wave, lane) == ascending original index. Block 11 stores M and
// sentinel-pads pts[M..QP). best[]-init spread across grid. Also zeroes the
// 14 per-column done counters + finalize ticket (the dispatch boundary
// guarantees they are 0 before any increment).
// ---------------------------------------------------------------------------
__global__ __launch_bounds__(1024) void build_kernel(
    const float* __restrict__ new_xyz,
    const float* __restrict__ gt_sdf,
    float4* __restrict__ pts,
    int* __restrict__ cj,
    int* __restrict__ Mout,
    ull* __restrict__ best,
    unsigned int* __restrict__ done,
    unsigned int* __restrict__ ticket)
{
    const int tid = threadIdx.x;
    const int b = blockIdx.x;        // 0..11
    const int lane = tid & 63;
    const int wave = tid >> 6;       // 0..15

    // global prefix: #inside in [0, b*1024), redundant per block
    int cpre = 0;
    #pragma unroll
    for (int r = 0; r < BB - 1; ++r) {
        const float sv = (r < b) ? gt_sdf[r * BT + tid] : 1.0f;
        cpre += (sv < 1e-8f) ? 1 : 0;
    }
    #pragma unroll
    for (int off = 32; off > 0; off >>= 1)
        cpre += __shfl_down(cpre, off, 64);      // lane0: wave partial

    // own range: flags + wave ballot rank
    const int idx = b * BT + tid;
    const float px = new_xyz[3 * idx + 0];
    const float py = new_xyz[3 * idx + 1];
    const float pz = new_xyz[3 * idx + 2];
    const bool ins = gt_sdf[idx] < 1e-8f;
    const ull m = __ballot(ins);
    const int rank = __popcll(m & ((1ull << lane) - 1ull));

    __shared__ int wpre[16];
    __shared__ int wcnt[16];
    __shared__ int woff[16];
    __shared__ int tot_s;
    if (lane == 0) { wpre[wave] = cpre; wcnt[wave] = __popcll(m); }
    __syncthreads();
    if (tid == 0) {
        int cb = 0;
        for (int w = 0; w < 16; ++w) cb += wpre[w];
        int run = cb;
        for (int w = 0; w < 16; ++w) { woff[w] = run; run += wcnt[w]; }
        tot_s = run;
    }
    __syncthreads();

    const int slot = woff[wave] + rank;
    if (ins && slot < QP) {
        pts[slot] = make_float4(-2.0f * px, -2.0f * py, -2.0f * pz,
                                px * px + py * py + pz * pz);
        cj[slot] = idx;
    }

    const int gid = b * BT + tid;
    if (gid < QP) best[gid] = ~0ull;
    if (gid < NQB) done[gid] = 0u;
    if (gid == NQB) *ticket = 0u;

    if (b == BB - 1) {
        const int M = tot_s;
        if (tid == 0) *Mout = M;
        for (int s = M + tid; s < QP; s += BT)
            pts[s] = make_float4(0.0f, 0.0f, 0.0f, 3e30f);
    }
}

// ---------------------------------------------------------------------------
// Kernel 2: NN + last-arrival loss. Grid (qb, s) as round 3; the NN phase is
// byte-identical to round 3 (LDS tile, fma z,y,x, strict <, device atomicMin
// of packed monotone-key<<32|idx into best[ci] => winner == sequential min,
// ties -> smallest j). After each block's atomics drain, tid0 increments
// done[qb]; the 56th arriver for column qb (and only it — NO block ever
// spins or waits) runs the loss for queries [qb*512,+512): best[ci] for that
// column is complete because exactly those 56 blocks write it (threadfence
// release before the add, threadfence acquire after — the same pattern as
// the verified ticket finalize). Partials 2qb/2qb+1 use the identical
// lane->query mapping and 4-wave shuffle tree as round 3's loss blocks;
// last of the 14 winners (ticket) does the verbatim 28-partial finalize.
// ---------------------------------------------------------------------------
template<bool CAREFUL>
__device__ __forceinline__ void nn_inner(
    const float4* __restrict__ tile,
    const float* wx, const float* wy, const float* wz,
    const int* kx,
    float* bd, int* bk)
{
    #pragma unroll 8
    for (int k = 0; k < TILE; ++k) {
        const float4 b = tile[k];
        #pragma unroll
        for (int a = 0; a < ACCS; ++a) {
            float t = fmaf(wz[a], b.z, b.w);
            t = fmaf(wy[a], b.y, t);
            t = fmaf(wx[a], b.x, t);
            bool ok = t < bd[a];
            if (CAREFUL) ok = ok && (k != kx[a]);
            if (ok) { bd[a] = t; bk[a] = k; }
        }
    }
}

__global__ __launch_bounds__(256, 4) void nn_loss_kernel(
    const float* __restrict__ new_xyz,
    const float* __restrict__ xyz,
    const float4* __restrict__ pts,
    const int* __restrict__ cj,
    const int* __restrict__ Mptr,
    ull* __restrict__ best,
    unsigned int* __restrict__ done,
    unsigned int* __restrict__ ticket,
    double* __restrict__ partial_sum,
    unsigned int* __restrict__ partial_cnt,
    float* __restrict__ out,
    CMat C)
{
    const int tid = threadIdx.x;
    const int qb = blockIdx.x;       // 0..13
    const int s = blockIdx.y;        // 0..55
    const int qbase = qb * QBLK;
    const int jb = s * TILE;
    const int lane = tid & 63;
    const int wid = tid >> 6;
    const int M = *Mptr;

    __shared__ float4 tile[TILE];
    __shared__ bool swin, sdone;
    __shared__ double wsum[4];
    __shared__ unsigned wcnt2[4];

    // ===================== NN phase (round-3 verbatim) =====================
    if (jb < M && qbase < M) {               // block-uniform work guard
        float wx[ACCS], wy[ACCS], wz[ACCS];
        int kx[ACCS];
        #pragma unroll
        for (int a = 0; a < ACCS; ++a) {
            const int ci = qbase + tid + a * 256;
            const float4 q = pts[ci];
            wx[a] = -0.5f * q.x;             // recover raw coords
            wy[a] = -0.5f * q.y;
            wz[a] = -0.5f * q.z;
            kx[a] = ci - jb;                 // self position in this split
        }

        if (tid < TILE) tile[tid] = pts[jb + tid];
        __syncthreads();

        float bd[ACCS];
        int bk[ACCS];
        #pragma unroll
        for (int a = 0; a < ACCS; ++a) { bd[a] = 3.0e38f; bk[a] = 0; }

        const bool dirty = (jb < qbase + QBLK) && (jb + TILE > qbase);
        if (dirty)
            nn_inner<true>(tile, wx, wy, wz, kx, bd, bk);
        else
            nn_inner<false>(tile, wx, wy, wz, kx, bd, bk);

        #pragma unroll
        for (int a = 0; a < ACCS; ++a) {
            const int ci = qbase + tid + a * 256;
            unsigned u = __float_as_uint(bd[a]);
            u = ((int)u < 0) ? ~u : (u | 0x80000000u);
            const ull v = ((ull)u << 32) | (ull)(unsigned)(jb + bk[a]);
            atomicMin(&best[ci], v);         // device scope on gfx950
        }
    }

    // ============= last-arrival handoff (no waiting, ever) =================
    __syncthreads();                          // all lanes' atomics issued+drained
    if (tid == 0) {
        __threadfence();                      // release our atomicMins
        const unsigned t = atomicAdd(&done[qb], 1u);
        swin = (t == NSPLIT - 1);             // 56th arriver owns the column
    }
    __syncthreads();
    if (!swin) return;                        // 770/784 blocks exit here

    __threadfence();                          // acquire: column best[] complete

    // ================= loss for queries [qbase, qbase+512) =================
    #pragma unroll
    for (int a = 0; a < 2; ++a) {
        const int ci = qbase + a * 256 + tid; // == round-3 loss block 2qb+a
        const ull b64 = best[ci];
        const bool real = (ci < M);

        const unsigned u = (unsigned)(b64 >> 32);
        const unsigned bits = (u & 0x80000000u) ? (u ^ 0x80000000u) : ~u;
        const float key = __uint_as_float(bits);   // min (sqj - 2*dot)
        const int cc = real ? (int)(unsigned)(b64 & 0xffffffffu) : 0;

        const int i  = real ? cj[ci] : 0;
        const int nn = cj[cc];

        const float wix = new_xyz[3 * i + 0];
        const float wiy = new_xyz[3 * i + 1];
        const float wiz = new_xyz[3 * i + 2];
        const float sqi = wix * wix + wiy * wiy + wiz * wiz;

        const float d2 = sqi + key;
        const float nnd = sqrtf(fmaxf(d2, 0.0f));
        const bool valid = real && (nnd > 1e-8f);

        float q = 0.0f;
        if (valid) {
            const float xix = xyz[3 * i + 0], xiy = xyz[3 * i + 1], xiz = xyz[3 * i + 2];
            const float wnx = new_xyz[3 * nn + 0], wny = new_xyz[3 * nn + 1], wnz = new_xyz[3 * nn + 2];
            const float xnx = xyz[3 * nn + 0],     xny = xyz[3 * nn + 1],     xnz = xyz[3 * nn + 2];

            const float du = (wnx - xnx) - (wix - xix);
            const float dv = (wny - xny) - (wiy - xiy);
            const float dw = (wnz - xnz) - (wiz - xiz);
            const float dx = wnx - wix + 1e-8f;
            const float dy = wny - wiy + 1e-8f;
            const float dz = wnz - wiz + 1e-8f;

            float et[6];
            et[0] = du / dx;
            et[1] = dv / dy;
            et[2] = dw / dz;
            et[3] = (du / dy + dv / dx) * 0.5f;
            et[4] = (du / dz + dw / dx) * 0.5f;
            et[5] = (dw / dy + dv / dz) * 0.5f;

            #pragma unroll
            for (int aa = 0; aa < 6; ++aa) {
                float s2 = 0.0f;
                #pragma unroll
                for (int b2 = 0; b2 < 6; ++b2) s2 += C.c[aa][b2] * et[b2];
                q += et[aa] * s2;
            }
        }

        // identical 64-lane shuffle tree + 4-wave LDS handoff as round 3
        double q2 = (double)q * (double)q;
        #pragma unroll
        for (int off = 32; off > 0; off >>= 1)
            q2 += __shfl_down(q2, off, 64);
        const ull vm = __ballot(valid);
        if (lane == 0) { wsum[wid] = q2; wcnt2[wid] = (unsigned)__popcll(vm); }
        __syncthreads();
        if (tid == 0) {
            partial_sum[2 * qb + a] = wsum[0] + wsum[1] + wsum[2] + wsum[3];
            partial_cnt[2 * qb + a] = wcnt2[0] + wcnt2[1] + wcnt2[2] + wcnt2[3];
        }
        __syncthreads();                      // wsum reuse between a=0/a=1
    }

    // ================= finalize: last of the 14 winners ====================
    if (tid == 0) {
        __threadfence();                      // release partials
        const unsigned t = atomicAdd(ticket, 1u);
        sdone = (t == NQB - 1);
    }
    __syncthreads();

    if (sdone && tid < 64) {
        __threadfence();                      // acquire side
        double ss = (tid < NPART) ? partial_sum[tid] : 0.0;
        double cc2 = (tid < NPART) ? (double)partial_cnt[tid] : 0.0;
        #pragma unroll
        for (int off = 32; off > 0; off >>= 1) {
            ss += __shfl_down(ss, off, 64);
            cc2 += __shfl_down(cc2, off, 64);
        }
        if (tid == 0) out[0] = (float)(sqrt(ss) / cc2);
    }
}

// ---------------- Host: build C = inv(Ci) -----------------------------------
static void build_cmat(CMat* M)
{
    const double VP = 0.4, EP = 0.21;
    double A[6][12];
    memset(A, 0, sizeof(A));
    double Ci[6][6];
    memset(Ci, 0, sizeof(Ci));
    Ci[0][0] = 1.0 / EP; Ci[0][1] = -VP / EP; Ci[0][2] = -VP / EP;
    Ci[1][0] = -VP / EP; Ci[1][1] = 1.0 / EP; Ci[1][2] = -VP / EP;
    Ci[2][0] = -VP;      Ci[2][1] = -VP;      Ci[2][2] = 1.0 / EP;
    Ci[3][3] = 2.0 * (1.0 + VP) / EP;
    Ci[4][4] = Ci[3][3];
    Ci[5][5] = Ci[3][3];

    for (int i = 0; i < 6; ++i) {
        for (int j = 0; j < 6; ++j) A[i][j] = Ci[i][j];
        A[i][6 + i] = 1.0;
    }
    for (int col = 0; col < 6; ++col) {
        int piv = col;
        for (int r = col + 1; r < 6; ++r)
            if (fabs(A[r][col]) > fabs(A[piv][col])) piv = r;
        if (piv != col)
            for (int c = 0; c < 12; ++c) { double t = A[col][c]; A[col][c] = A[piv][c]; A[piv][c] = t; }
        const double d = A[col][col];
        for (int c = 0; c < 12; ++c) A[col][c] /= d;
        for (int r = 0; r < 6; ++r) {
            if (r == col) continue;
            const double f = A[r][col];
            if (f == 0.0) continue;
            for (int c = 0; c < 12; ++c) A[r][c] -= f * A[col][c];
        }
    }
    for (int i = 0; i < 6; ++i)
        for (int j = 0; j < 6; ++j)
            M->c[i][j] = (float)A[i][6 + j];
}

extern "C" void kernel_launch(void* const* d_in, const int* in_sizes, int n_in,
                              void* d_out, int out_size, void* d_ws, size_t ws_size,
                              hipStream_t stream)
{
    const float* new_xyz = (const float*)d_in[0];
    const float* xyz     = (const float*)d_in[1];
    const float* gt_sdf  = (const float*)d_in[2];
    float* out = (float*)d_out;

    // workspace layout (all consumed slots written before read):
    //   [0,      QP*16) : pts  float4 compacted inside points   (112 KB)
    //   [+,      QP*4)  : cj   original indices                 (28 KB)
    //   [+,      16)    : M    compact count
    //   [+,      QP*8)  : best u64 per-query NN minimum         (56 KB)
    //   then NPART doubles + NPART uints + NQB done counters + 1 ticket
    char* p = (char*)d_ws;
    float4* pts = (float4*)p;                    p += (size_t)QP * 16;
    int* cj = (int*)p;                           p += (size_t)QP * 4;
    int* Mptr = (int*)p;                         p += 16;
    ull* best = (ull*)p;                         p += (size_t)QP * 8;
    double* partial_sum = (double*)p;            p += NPART * sizeof(double);
    unsigned int* partial_cnt = (unsigned int*)p; p += NPART * sizeof(unsigned int);
    unsigned int* done = (unsigned int*)p;       p += NQB * sizeof(unsigned int);
    unsigned int* ticket = (unsigned int*)p;

    CMat C;
    build_cmat(&C);

    build_kernel<<<BB, BT, 0, stream>>>(new_xyz, gt_sdf, pts, cj, Mptr, best,
                                        done, ticket);
    nn_loss_kernel<<<dim3(NQB, NSPLIT), 256, 0, stream>>>(
        new_xyz, xyz, pts, cj, Mptr, best, done, ticket,
        partial_sum, partial_cnt, out, C);
}

// Round 9
// 81.617 us; speedup vs baseline: 1.8266x; 1.0941x over previous
//
#include <hip/hip_runtime.h>
#include <math.h>
#include <string.h>

#define N 12288
#define QP 7168           // padded compact count = 28*256
#define TILE 256          // candidates per split (LDS tile)
#define NSPLIT 28         // QP / TILE
#define ACCS 2            // queries per thread
#define QBLK 512          // queries per block
#define NQB 14            // QP / QBLK
#define BT 1024           // build-kernel threads per block
#define BB 12             // build-kernel blocks (N / BT)
#define NPART (QP / 256)  // 28 loss blocks

typedef unsigned long long ull;

struct CMat { float c[6][6]; };

// ---------------------------------------------------------------------------
// Kernel 1: order-preserving compaction of inside points (round-3 verbatim).
// Block b owns [b*1024,(b+1)*1024); global write base computed redundantly
// (recount sdf of blocks [0,b): block-uniform predicated loads, L2-broadcast)
// + per-thread count + shuffle/LDS reduce. Ordering key (block, wave, lane)
// == ascending original index => bit-identical compaction. Block 11 stores M
// and sentinel-pads pts[M..QP); best[]-init and ticket reset spread across
// the grid.
// ---------------------------------------------------------------------------
__global__ __launch_bounds__(1024) void build_kernel(
    const float* __restrict__ new_xyz,
    const float* __restrict__ gt_sdf,
    float4* __restrict__ pts,
    int* __restrict__ cj,
    int* __restrict__ Mout,
    ull* __restrict__ best,
    unsigned int* __restrict__ ticket)
{
    const int tid = threadIdx.x;
    const int b = blockIdx.x;        // 0..11
    const int lane = tid & 63;
    const int wave = tid >> 6;       // 0..15

    // global prefix: #inside in [0, b*1024), redundant per block
    int cpre = 0;
    #pragma unroll
    for (int r = 0; r < BB - 1; ++r) {
        const float sv = (r < b) ? gt_sdf[r * BT + tid] : 1.0f;
        cpre += (sv < 1e-8f) ? 1 : 0;
    }
    #pragma unroll
    for (int off = 32; off > 0; off >>= 1)
        cpre += __shfl_down(cpre, off, 64);      // lane0: wave partial

    // own range: flags + wave ballot rank
    const int idx = b * BT + tid;
    const float px = new_xyz[3 * idx + 0];
    const float py = new_xyz[3 * idx + 1];
    const float pz = new_xyz[3 * idx + 2];
    const bool ins = gt_sdf[idx] < 1e-8f;
    const ull m = __ballot(ins);
    const int rank = __popcll(m & ((1ull << lane) - 1ull));

    __shared__ int wpre[16];
    __shared__ int wcnt[16];
    __shared__ int woff[16];
    __shared__ int tot_s;
    if (lane == 0) { wpre[wave] = cpre; wcnt[wave] = __popcll(m); }
    __syncthreads();
    if (tid == 0) {
        int cb = 0;
        for (int w = 0; w < 16; ++w) cb += wpre[w];
        int run = cb;
        for (int w = 0; w < 16; ++w) { woff[w] = run; run += wcnt[w]; }
        tot_s = run;
    }
    __syncthreads();

    const int slot = woff[wave] + rank;
    if (ins && slot < QP) {
        pts[slot] = make_float4(-2.0f * px, -2.0f * py, -2.0f * pz,
                                px * px + py * py + pz * pz);
        cj[slot] = idx;
    }

    const int gid = b * BT + tid;
    if (gid < QP) best[gid] = ~0ull;
    if (gid == 0) *ticket = 0u;

    if (b == BB - 1) {
        const int M = tot_s;
        if (tid == 0) *Mout = M;
        for (int s = M + tid; s < QP; s += BT)
            pts[s] = make_float4(0.0f, 0.0f, 0.0f, 3e30f);
    }
}

// ---------------------------------------------------------------------------
// Kernel 2: NN among compacted points. TILE=256 (vs r3's 128): same total
// pair count, but HALF the splits => half the device atomicMins (200k) and
// half the redundant query reloads. Winner equivalence: strict < over
// ascending k within a split = leftmost-in-split; cross-split u64 min of
// (monotone-key<<32 | jb+bk) = global leftmost min — identical winner and
// tie-break for any split size. Everything else round-3 verbatim.
// ---------------------------------------------------------------------------
template<bool CAREFUL>
__device__ __forceinline__ void nn_inner(
    const float4* __restrict__ tile,
    const float* wx, const float* wy, const float* wz,
    const int* kx,
    float* bd, int* bk)
{
    #pragma unroll 8
    for (int k = 0; k < TILE; ++k) {
        const float4 b = tile[k];
        #pragma unroll
        for (int a = 0; a < ACCS; ++a) {
            float t = fmaf(wz[a], b.z, b.w);
            t = fmaf(wy[a], b.y, t);
            t = fmaf(wx[a], b.x, t);
            bool ok = t < bd[a];
            if (CAREFUL) ok = ok && (k != kx[a]);
            if (ok) { bd[a] = t; bk[a] = k; }
        }
    }
}

__global__ __launch_bounds__(256, 4) void nn_kernel(
    const float4* __restrict__ pts,
    const int* __restrict__ Mptr,
    ull* __restrict__ best)
{
    const int tid = threadIdx.x;
    const int qbase = blockIdx.x * QBLK;
    const int jb = blockIdx.y * TILE;

    const int M = *Mptr;
    if (jb >= M || qbase >= M) return;   // uniform: whole block exits

    float wx[ACCS], wy[ACCS], wz[ACCS];
    int kx[ACCS];
    #pragma unroll
    for (int a = 0; a < ACCS; ++a) {
        const int ci = qbase + tid + a * 256;
        const float4 q = pts[ci];
        wx[a] = -0.5f * q.x;           // recover raw coords from transform
        wy[a] = -0.5f * q.y;
        wz[a] = -0.5f * q.z;
        kx[a] = ci - jb;               // self position within this split
    }

    __shared__ float4 tile[TILE];
    tile[tid] = pts[jb + tid];         // TILE == blockDim
    __syncthreads();

    float bd[ACCS];
    int bk[ACCS];
    #pragma unroll
    for (int a = 0; a < ACCS; ++a) { bd[a] = 3.0e38f; bk[a] = 0; }

    const bool dirty = (jb < qbase + QBLK) && (jb + TILE > qbase);
    if (dirty)
        nn_inner<true>(tile, wx, wy, wz, kx, bd, bk);
    else
        nn_inner<false>(tile, wx, wy, wz, kx, bd, bk);

    #pragma unroll
    for (int a = 0; a < ACCS; ++a) {
        const int ci = qbase + tid + a * 256;
        unsigned u = __float_as_uint(bd[a]);
        u = ((int)u < 0) ? ~u : (u | 0x80000000u);
        const ull v = ((ull)u << 32) | (ull)(unsigned)(jb + bk[a]);
        atomicMin(&best[ci], v);       // device-scope by default on gfx950
    }
}

// ---------------------------------------------------------------------------
// Kernel 3: per-query NN lookup (single u64 load) + strain quadratic form +
// block partials + fused last-block finalize (threadfence+ticket).
// Round-3 verbatim => bit-identical output.
// ---------------------------------------------------------------------------
__global__ __launch_bounds__(256) void loss_kernel(
    const float* __restrict__ new_xyz,
    const float* __restrict__ xyz,
    const int* __restrict__ cj,
    const int* __restrict__ Mptr,
    const ull* __restrict__ best_arr,
    double* __restrict__ partial_sum,
    unsigned int* __restrict__ partial_cnt,
    unsigned int* __restrict__ ticket,
    float* __restrict__ out,
    CMat C)
{
    const int tid = threadIdx.x;
    const int ci = blockIdx.x * 256 + tid;

    const ull best = best_arr[ci];
    const int M = *Mptr;
    const bool real = (ci < M);

    const unsigned u = (unsigned)(best >> 32);
    const unsigned bits = (u & 0x80000000u) ? (u ^ 0x80000000u) : ~u;
    const float key = __uint_as_float(bits);   // min (sqj - 2*dot)
    const int cc = real ? (int)(unsigned)(best & 0xffffffffu) : 0;

    const int i  = real ? cj[ci] : 0;
    const int nn = cj[cc];

    const float wix = new_xyz[3 * i + 0];
    const float wiy = new_xyz[3 * i + 1];
    const float wiz = new_xyz[3 * i + 2];
    const float sqi = wix * wix + wiy * wiy + wiz * wiz;

    const float d2 = sqi + key;
    const float nnd = sqrtf(fmaxf(d2, 0.0f));
    const bool valid = real && (nnd > 1e-8f);   // inside guaranteed by build

    float q = 0.0f;
    if (valid) {
        const float xix = xyz[3 * i + 0], xiy = xyz[3 * i + 1], xiz = xyz[3 * i + 2];
        const float wnx = new_xyz[3 * nn + 0], wny = new_xyz[3 * nn + 1], wnz = new_xyz[3 * nn + 2];
        const float xnx = xyz[3 * nn + 0],     xny = xyz[3 * nn + 1],     xnz = xyz[3 * nn + 2];

        const float du = (wnx - xnx) - (wix - xix);
        const float dv = (wny - xny) - (wiy - xiy);
        const float dw = (wnz - xnz) - (wiz - xiz);
        const float dx = wnx - wix + 1e-8f;
        const float dy = wny - wiy + 1e-8f;
        const float dz = wnz - wiz + 1e-8f;

        float et[6];
        et[0] = du / dx;
        et[1] = dv / dy;
        et[2] = dw / dz;
        et[3] = (du / dy + dv / dx) * 0.5f;
        et[4] = (du / dz + dw / dx) * 0.5f;
        et[5] = (dw / dy + dv / dz) * 0.5f;

        #pragma unroll
        for (int a = 0; a < 6; ++a) {
            float s2 = 0.0f;
            #pragma unroll
            for (int b2 = 0; b2 < 6; ++b2) s2 += C.c[a][b2] * et[b2];
            q += et[a] * s2;
        }
    }

    // block reduction: wave shuffle + LDS handoff (unchanged order)
    double q2 = (double)q * (double)q;
    #pragma unroll
    for (int off = 32; off > 0; off >>= 1)
        q2 += __shfl_down(q2, off, 64);
    const ull vm = __ballot(valid);
    const int lane = tid & 63;
    const int wid = tid >> 6;

    __shared__ double wsum[4];
    __shared__ unsigned wcnt2[4];
    __shared__ bool sdone;
    if (lane == 0) { wsum[wid] = q2; wcnt2[wid] = (unsigned)__popcll(vm); }
    __syncthreads();
    if (tid == 0) {
        partial_sum[blockIdx.x] = wsum[0] + wsum[1] + wsum[2] + wsum[3];
        partial_cnt[blockIdx.x] = wcnt2[0] + wcnt2[1] + wcnt2[2] + wcnt2[3];
        __threadfence();                       // release partials device-wide
        const unsigned t = atomicAdd(ticket, 1u);
        sdone = (t == NPART - 1);              // last block finalizes
    }
    __syncthreads();

    if (sdone && tid < 64) {
        __threadfence();                       // acquire side
        double s = (tid < NPART) ? partial_sum[tid] : 0.0;
        double c = (tid < NPART) ? (double)partial_cnt[tid] : 0.0;
        #pragma unroll
        for (int off = 32; off > 0; off >>= 1) {
            s += __shfl_down(s, off, 64);
            c += __shfl_down(c, off, 64);
        }
        if (tid == 0) out[0] = (float)(sqrt(s) / c);
    }
}

// ---------------- Host: build C = inv(Ci) -----------------------------------
static void build_cmat(CMat* M)
{
    const double VP = 0.4, EP = 0.21;
    double A[6][12];
    memset(A, 0, sizeof(A));
    double Ci[6][6];
    memset(Ci, 0, sizeof(Ci));
    Ci[0][0] = 1.0 / EP; Ci[0][1] = -VP / EP; Ci[0][2] = -VP / EP;
    Ci[1][0] = -VP / EP; Ci[1][1] = 1.0 / EP; Ci[1][2] = -VP / EP;
    Ci[2][0] = -VP;      Ci[2][1] = -VP;      Ci[2][2] = 1.0 / EP;
    Ci[3][3] = 2.0 * (1.0 + VP) / EP;
    Ci[4][4] = Ci[3][3];
    Ci[5][5] = Ci[3][3];

    for (int i = 0; i < 6; ++i) {
        for (int j = 0; j < 6; ++j) A[i][j] = Ci[i][j];
        A[i][6 + i] = 1.0;
    }
    for (int col = 0; col < 6; ++col) {
        int piv = col;
        for (int r = col + 1; r < 6; ++r)
            if (fabs(A[r][col]) > fabs(A[piv][col])) piv = r;
        if (piv != col)
            for (int c = 0; c < 12; ++c) { double t = A[col][c]; A[col][c] = A[piv][c]; A[piv][c] = t; }
        const double d = A[col][col];
        for (int c = 0; c < 12; ++c) A[col][c] /= d;
        for (int r = 0; r < 6; ++r) {
            if (r == col) continue;
            const double f = A[r][col];
            if (f == 0.0) continue;
            for (int c = 0; c < 12; ++c) A[r][c] -= f * A[col][c];
        }
    }
    for (int i = 0; i < 6; ++i)
        for (int j = 0; j < 6; ++j)
            M->c[i][j] = (float)A[i][6 + j];
}

extern "C" void kernel_launch(void* const* d_in, const int* in_sizes, int n_in,
                              void* d_out, int out_size, void* d_ws, size_t ws_size,
                              hipStream_t stream)
{
    const float* new_xyz = (const float*)d_in[0];
    const float* xyz     = (const float*)d_in[1];
    const float* gt_sdf  = (const float*)d_in[2];
    float* out = (float*)d_out;

    // workspace layout (all consumed slots written before read):
    //   [0,      QP*16) : pts  float4 compacted inside points   (112 KB)
    //   [+,      QP*4)  : cj   original indices                 (28 KB)
    //   [+,      16)    : M    compact count
    //   [+,      QP*8)  : best u64 per-query NN minimum         (56 KB)
    //   then NPART doubles + NPART uints + 1 uint ticket
    char* p = (char*)d_ws;
    float4* pts = (float4*)p;                    p += (size_t)QP * 16;
    int* cj = (int*)p;                           p += (size_t)QP * 4;
    int* Mptr = (int*)p;                         p += 16;
    ull* best = (ull*)p;                         p += (size_t)QP * 8;
    double* partial_sum = (double*)p;            p += NPART * sizeof(double);
    unsigned int* partial_cnt = (unsigned int*)p;

    CMat C;
    build_cmat(&C);

    build_kernel<<<BB, BT, 0, stream>>>(new_xyz, gt_sdf, pts, cj, Mptr, best,
                                        (unsigned int*)(partial_cnt + NPART));
    nn_kernel<<<dim3(NQB, NSPLIT), 256, 0, stream>>>(pts, Mptr, best);
    loss_kernel<<<QP / 256, 256, 0, stream>>>(new_xyz, xyz, cj, Mptr, best,
                                              partial_sum, partial_cnt,
                                              (unsigned int*)(partial_cnt + NPART),
                                              out, C);
}

// Round 10
// 76.492 us; speedup vs baseline: 1.9490x; 1.0670x over previous
//
#include <hip/hip_runtime.h>
#include <math.h>
#include <string.h>

#define N 12288
#define QP 7168           // padded compact count = 56*128 (E[M]=6144, +18 sigma)
#define TILE 128          // candidates per split (LDS tile)
#define NSPLIT 56         // QP / TILE
#define ACCS 2            // queries per thread
#define QBLK 512          // queries per block
#define NQB 14            // QP / QBLK
#define BT 1024           // build-kernel threads per block
#define BB 12             // build-kernel blocks (N / BT)
#define NPART (QP / 256)  // 28 loss blocks

typedef unsigned long long ull;

struct CMat { float c[6][6]; };

// ---------------------------------------------------------------------------
// Kernel 1: order-preserving compaction of inside points, MULTI-BLOCK with
// zero cross-block communication. Block b owns indices [b*1024, (b+1)*1024).
// Its global write base = #inside in [0, b*1024), computed REDUNDANTLY by
// re-reading the sdf slices of blocks [0, b) (block-uniform predicated loads,
// L2-broadcast across the 12 blocks) + per-thread count + shuffle/LDS reduce.
// Ordering key (block, wave, lane) == ascending original index => compaction
// bit-identical to the original single-block scheme. Block 11 (which computes
// the full total M) writes Mout + the pts sentinel pad; best[]-init and
// ticket reset are spread across the grid.
// ---------------------------------------------------------------------------
__global__ __launch_bounds__(1024) void build_kernel(
    const float* __restrict__ new_xyz,
    const float* __restrict__ gt_sdf,
    float4* __restrict__ pts,
    int* __restrict__ cj,
    int* __restrict__ Mout,
    ull* __restrict__ best,
    unsigned int* __restrict__ ticket)
{
    const int tid = threadIdx.x;
    const int b = blockIdx.x;        // 0..11
    const int lane = tid & 63;
    const int wave = tid >> 6;       // 0..15

    // ---- global prefix: count inside over [0, b*1024) (redundant per block)
    int cpre = 0;
    #pragma unroll
    for (int r = 0; r < BB - 1; ++r) {
        // block-uniform predicate: no divergence; r>=b rounds contribute 0
        const float sv = (r < b) ? gt_sdf[r * BT + tid] : 1.0f;
        cpre += (sv < 1e-8f) ? 1 : 0;
    }
    #pragma unroll
    for (int off = 32; off > 0; off >>= 1)
        cpre += __shfl_down(cpre, off, 64);      // lane0: wave partial

    // ---- own range: flags + wave ballot rank (ordering within block)
    const int idx = b * BT + tid;
    const float px = new_xyz[3 * idx + 0];
    const float py = new_xyz[3 * idx + 1];
    const float pz = new_xyz[3 * idx + 2];
    const bool ins = gt_sdf[idx] < 1e-8f;
    const ull m = __ballot(ins);
    const int rank = __popcll(m & ((1ull << lane) - 1ull));

    __shared__ int wpre[16];   // per-wave partials of cpre
    __shared__ int wcnt[16];   // per-wave own-range inside counts
    __shared__ int woff[16];   // exclusive offsets (incl. global prefix)
    __shared__ int tot_s;      // cpre_block + own block count
    if (lane == 0) { wpre[wave] = cpre; wcnt[wave] = __popcll(m); }
    __syncthreads();
    if (tid == 0) {
        int cb = 0;
        for (int w = 0; w < 16; ++w) cb += wpre[w];   // count in [0, b*1024)
        int run = cb;
        for (int w = 0; w < 16; ++w) { woff[w] = run; run += wcnt[w]; }
        tot_s = run;                                  // for b==11 this is M
    }
    __syncthreads();

    const int slot = woff[wave] + rank;
    if (ins && slot < QP) {
        pts[slot] = make_float4(-2.0f * px, -2.0f * py, -2.0f * pz,
                                px * px + py * py + pz * pz);
        cj[slot] = idx;
    }

    // ---- spread initialization across the grid
    const int gid = b * BT + tid;                 // 0..12287
    if (gid < QP) best[gid] = ~0ull;
    if (gid == 0) *ticket = 0u;

    if (b == BB - 1) {
        const int M = tot_s;
        if (tid == 0) *Mout = M;
        for (int s = M + tid; s < QP; s += BT)
            pts[s] = make_float4(0.0f, 0.0f, 0.0f, 3e30f);
    }
}

// ---------------------------------------------------------------------------
// Kernel 2: NN among compacted points. Block (qb, s): queries
// [qb*512, +512) (2/thread), candidates split s = [s*128, +128) in LDS.
// d' = sqj - 2*dot via fma chain (z,y,x — unchanged rounding).
// Cross-split combine via device-scope u64 atomicMin into best[ci]:
// key (monotone float bits)<<32 | compact-idx — min is order-independent and
// idx makes values unique => winner bit-identical to a sequential min
// (ties -> smallest compact idx == smallest j). Blocks entirely in the
// sentinel pad (>= M) exit early.
// ---------------------------------------------------------------------------
template<bool CAREFUL>
__device__ __forceinline__ void nn_inner(
    const float4* __restrict__ tile,
    const float* wx, const float* wy, const float* wz,
    const int* kx,
    float* bd, int* bk)
{
    #pragma unroll 8
    for (int k = 0; k < TILE; ++k) {
        const float4 b = tile[k];
        #pragma unroll
        for (int a = 0; a < ACCS; ++a) {
            float t = fmaf(wz[a], b.z, b.w);
            t = fmaf(wy[a], b.y, t);
            t = fmaf(wx[a], b.x, t);
            bool ok = t < bd[a];
            if (CAREFUL) ok = ok && (k != kx[a]);
            if (ok) { bd[a] = t; bk[a] = k; }
        }
    }
}

__global__ __launch_bounds__(256, 4) void nn_kernel(
    const float4* __restrict__ pts,
    const int* __restrict__ Mptr,
    ull* __restrict__ best)
{
    const int tid = threadIdx.x;
    const int qbase = blockIdx.x * QBLK;
    const int s = blockIdx.y;
    const int jb = s * TILE;

    const int M = *Mptr;
    if (jb >= M || qbase >= M) return;   // uniform: whole block exits

    float wx[ACCS], wy[ACCS], wz[ACCS];
    int kx[ACCS];
    #pragma unroll
    for (int a = 0; a < ACCS; ++a) {
        const int ci = qbase + tid + a * 256;
        const float4 q = pts[ci];
        wx[a] = -0.5f * q.x;           // recover raw coords from transform
        wy[a] = -0.5f * q.y;
        wz[a] = -0.5f * q.z;
        kx[a] = ci - jb;               // self position within this split
    }

    __shared__ float4 tile[TILE];
    if (tid < TILE) tile[tid] = pts[jb + tid];
    __syncthreads();

    float bd[ACCS];
    int bk[ACCS];
    #pragma unroll
    for (int a = 0; a < ACCS; ++a) { bd[a] = 3.0e38f; bk[a] = 0; }

    const bool dirty = (jb < qbase + QBLK) && (jb + TILE > qbase);
    if (dirty)
        nn_inner<true>(tile, wx, wy, wz, kx, bd, bk);
    else
        nn_inner<false>(tile, wx, wy, wz, kx, bd, bk);

    #pragma unroll
    for (int a = 0; a < ACCS; ++a) {
        const int ci = qbase + tid + a * 256;
        unsigned u = __float_as_uint(bd[a]);
        u = ((int)u < 0) ? ~u : (u | 0x80000000u);
        const ull v = ((ull)u << 32) | (ull)(unsigned)(jb + bk[a]);
        atomicMin(&best[ci], v);       // device-scope by default on gfx950
    }
}

// ---------------------------------------------------------------------------
// Kernel 3: per-query NN lookup (single u64 load) + strain quadratic form +
// block partials + fused last-block finalize (threadfence+ticket).
// Partial layout and the 28-partial shuffle-tree summation order are
// identical to the original separate final_kernel => bit-identical output.
// ---------------------------------------------------------------------------
__global__ __launch_bounds__(256) void loss_kernel(
    const float* __restrict__ new_xyz,
    const float* __restrict__ xyz,
    const int* __restrict__ cj,
    const int* __restrict__ Mptr,
    const ull* __restrict__ best_arr,
    double* __restrict__ partial_sum,
    unsigned int* __restrict__ partial_cnt,
    unsigned int* __restrict__ ticket,
    float* __restrict__ out,
    CMat C)
{
    const int tid = threadIdx.x;
    const int ci = blockIdx.x * 256 + tid;

    const ull best = best_arr[ci];
    const int M = *Mptr;
    const bool real = (ci < M);

    const unsigned u = (unsigned)(best >> 32);
    const unsigned bits = (u & 0x80000000u) ? (u ^ 0x80000000u) : ~u;
    const float key = __uint_as_float(bits);   // min (sqj - 2*dot)
    // fake queries may hold garbage/init values -> guard the index
    const int cc = real ? (int)(unsigned)(best & 0xffffffffu) : 0;

    const int i  = real ? cj[ci] : 0;
    const int nn = cj[cc];

    const float wix = new_xyz[3 * i + 0];
    const float wiy = new_xyz[3 * i + 1];
    const float wiz = new_xyz[3 * i + 2];
    const float sqi = wix * wix + wiy * wiy + wiz * wiz;

    const float d2 = sqi + key;
    const float nnd = sqrtf(fmaxf(d2, 0.0f));
    const bool valid = real && (nnd > 1e-8f);   // inside guaranteed by build

    float q = 0.0f;
    if (valid) {
        const float xix = xyz[3 * i + 0], xiy = xyz[3 * i + 1], xiz = xyz[3 * i + 2];
        const float wnx = new_xyz[3 * nn + 0], wny = new_xyz[3 * nn + 1], wnz = new_xyz[3 * nn + 2];
        const float xnx = xyz[3 * nn + 0],     xny = xyz[3 * nn + 1],     xnz = xyz[3 * nn + 2];

        const float du = (wnx - xnx) - (wix - xix);
        const float dv = (wny - xny) - (wiy - xiy);
        const float dw = (wnz - xnz) - (wiz - xiz);
        const float dx = wnx - wix + 1e-8f;
        const float dy = wny - wiy + 1e-8f;
        const float dz = wnz - wiz + 1e-8f;

        float et[6];
        et[0] = du / dx;
        et[1] = dv / dy;
        et[2] = dw / dz;
        et[3] = (du / dy + dv / dx) * 0.5f;
        et[4] = (du / dz + dw / dx) * 0.5f;
        et[5] = (dw / dy + dv / dz) * 0.5f;

        #pragma unroll
        for (int a = 0; a < 6; ++a) {
            float s2 = 0.0f;
            #pragma unroll
            for (int b2 = 0; b2 < 6; ++b2) s2 += C.c[a][b2] * et[b2];
            q += et[a] * s2;
        }
    }

    // block reduction: wave shuffle + LDS handoff (unchanged order)
    double q2 = (double)q * (double)q;
    #pragma unroll
    for (int off = 32; off > 0; off >>= 1)
        q2 += __shfl_down(q2, off, 64);
    const ull vm = __ballot(valid);
    const int lane = tid & 63;
    const int wid = tid >> 6;

    __shared__ double wsum[4];
    __shared__ unsigned wcnt2[4];
    __shared__ bool sdone;
    if (lane == 0) { wsum[wid] = q2; wcnt2[wid] = (unsigned)__popcll(vm); }
    __syncthreads();
    if (tid == 0) {
        partial_sum[blockIdx.x] = wsum[0] + wsum[1] + wsum[2] + wsum[3];
        partial_cnt[blockIdx.x] = wcnt2[0] + wcnt2[1] + wcnt2[2] + wcnt2[3];
        __threadfence();                       // release partials device-wide
        const unsigned t = atomicAdd(ticket, 1u);
        sdone = (t == NPART - 1);              // last block finalizes
    }
    __syncthreads();

    if (sdone && tid < 64) {
        __threadfence();                       // acquire side
        double s = (tid < NPART) ? partial_sum[tid] : 0.0;
        double c = (tid < NPART) ? (double)partial_cnt[tid] : 0.0;
        #pragma unroll
        for (int off = 32; off > 0; off >>= 1) {
            s += __shfl_down(s, off, 64);
            c += __shfl_down(c, off, 64);
        }
        if (tid == 0) out[0] = (float)(sqrt(s) / c);
    }
}

// ---------------- Host: build C = inv(Ci) -----------------------------------
static void build_cmat(CMat* M)
{
    const double VP = 0.4, EP = 0.21;
    double A[6][12];
    memset(A, 0, sizeof(A));
    double Ci[6][6];
    memset(Ci, 0, sizeof(Ci));
    Ci[0][0] = 1.0 / EP; Ci[0][1] = -VP / EP; Ci[0][2] = -VP / EP;
    Ci[1][0] = -VP / EP; Ci[1][1] = 1.0 / EP; Ci[1][2] = -VP / EP;
    Ci[2][0] = -VP;      Ci[2][1] = -VP;      Ci[2][2] = 1.0 / EP;
    Ci[3][3] = 2.0 * (1.0 + VP) / EP;
    Ci[4][4] = Ci[3][3];
    Ci[5][5] = Ci[3][3];

    for (int i = 0; i < 6; ++i) {
        for (int j = 0; j < 6; ++j) A[i][j] = Ci[i][j];
        A[i][6 + i] = 1.0;
    }
    for (int col = 0; col < 6; ++col) {
        int piv = col;
        for (int r = col + 1; r < 6; ++r)
            if (fabs(A[r][col]) > fabs(A[piv][col])) piv = r;
        if (piv != col)
            for (int c = 0; c < 12; ++c) { double t = A[col][c]; A[col][c] = A[piv][c]; A[piv][c] = t; }
        const double d = A[col][col];
        for (int c = 0; c < 12; ++c) A[col][c] /= d;
        for (int r = 0; r < 6; ++r) {
            if (r == col) continue;
            const double f = A[r][col];
            if (f == 0.0) continue;
            for (int c = 0; c < 12; ++c) A[r][c] -= f * A[col][c];
        }
    }
    for (int i = 0; i < 6; ++i)
        for (int j = 0; j < 6; ++j)
            M->c[i][j] = (float)A[i][6 + j];
}

extern "C" void kernel_launch(void* const* d_in, const int* in_sizes, int n_in,
                              void* d_out, int out_size, void* d_ws, size_t ws_size,
                              hipStream_t stream)
{
    const float* new_xyz = (const float*)d_in[0];
    const float* xyz     = (const float*)d_in[1];
    const float* gt_sdf  = (const float*)d_in[2];
    float* out = (float*)d_out;

    // workspace layout (all consumed slots written before read):
    //   [0,      QP*16) : pts  float4 compacted inside points   (112 KB)
    //   [+,      QP*4)  : cj   original indices                 (28 KB)
    //   [+,      16)    : M    compact count
    //   [+,      QP*8)  : best u64 per-query NN minimum         (56 KB)
    //   then NPART doubles + NPART uints + 1 uint ticket
    char* p = (char*)d_ws;
    float4* pts = (float4*)p;                    p += (size_t)QP * 16;
    int* cj = (int*)p;                           p += (size_t)QP * 4;
    int* Mptr = (int*)p;                         p += 16;
    ull* best = (ull*)p;                         p += (size_t)QP * 8;
    double* partial_sum = (double*)p;            p += NPART * sizeof(double);
    unsigned int* partial_cnt = (unsigned int*)p; p += NPART * sizeof(unsigned int);
    unsigned int* ticket = (unsigned int*)p;

    CMat C;
    build_cmat(&C);

    build_kernel<<<BB, BT, 0, stream>>>(new_xyz, gt_sdf, pts, cj, Mptr, best, ticket);
    nn_kernel<<<dim3(NQB, NSPLIT), 256, 0, stream>>>(pts, Mptr, best);
    loss_kernel<<<QP / 256, 256, 0, stream>>>(new_xyz, xyz, cj, Mptr, best,
                                              partial_sum, partial_cnt, ticket,
                                              out, C);
}